// Round 16
// baseline (72.396 us; speedup 1.0000x reference)
//
#include <hip/hip_runtime.h>
#include <hip/hip_bf16.h>

typedef __attribute__((ext_vector_type(8))) short short8;
typedef __attribute__((ext_vector_type(4))) float f32x4;
typedef __attribute__((ext_vector_type(4))) unsigned int u32x4;

#define C_TOT 256
#define O_TOT 256
#define HW_   784
#define NT_   128
#define KMAX  1792
#define KPAD_STD 320          // 304 real taps (128+80+96) padded to 32 -> 10 K-steps
#define XBYTES (NT_ * C_TOT * HW_ * 4)
#define MARKER 0x60000000u    // invalid-tap offset -> OOB for buffer bounds-check

// ws layout (bytes):
//   meta  u32[4]              @ 0
//   idx   u32[KMAX]           @ WS_IDX_OFF   (c | dtm<<8)
//   cval  f32[KMAX]           @ WS_CVAL_OFF
//   offt  u32[8][KMAX]        @ WS_OFFT_OFF  per-t relative byte offsets (or MARKER)
//   A3    bf16[(KMAX/8)*256*8]@ WS_A3_OFF    fragment-major: A3[(slot*256+o)*8+e]
#define WS_IDX_OFF  16
#define WS_CVAL_OFF (WS_IDX_OFF + 4 * KMAX)
#define WS_OFFT_OFF (WS_CVAL_OFF + 4 * KMAX)
#define WS_A3_OFF   (WS_OFFT_OFF + 4 * 8 * KMAX)

#if __has_builtin(__builtin_amdgcn_make_buffer_rsrc) && __has_builtin(__builtin_amdgcn_raw_buffer_load_b32)
#define USE_RAW_BUF 1
#else
#define USE_RAW_BUF 0
#endif

__device__ __forceinline__ unsigned int pk2(float lo, float hi) {
    float2 f; f.x = lo; f.y = hi;
    __hip_bfloat162 h = __float22bfloat162_rn(f);   // v_cvt_pk_bf16_f32
    unsigned int r;
    __builtin_memcpy(&r, &h, 4);
    return r;
}
__device__ __forceinline__ unsigned short f2b(float f) {
    union { float f; unsigned int u; } cv; cv.f = f;
    unsigned int u = cv.u;
    u += 0x7fffu + ((u >> 16) & 1u);
    return (unsigned short)(u >> 16);
}

// ---- pre-pass 1: tap enumeration + per-t offset tables ----
__global__ __launch_bounds__(256)
void build_idx(const float* __restrict__ w3, const float* __restrict__ w5,
               const float* __restrict__ w7, unsigned int* __restrict__ meta,
               unsigned int* __restrict__ idx, float* __restrict__ cval,
               unsigned int* __restrict__ offt)
{
    const int c = threadIdx.x;
    float cf[7];
    #pragma unroll
    for (int i = 0; i < 7; ++i) cf[i] = 0.f;
    if (c < 128) {
        #pragma unroll
        for (int i = 0; i < 3; ++i) cf[i + 2] = w3[c * 3 + i];
    } else if (c < 192) {
        #pragma unroll
        for (int i = 0; i < 5; ++i) cf[i + 1] = w5[(c - 128) * 5 + i];
    } else {
        #pragma unroll
        for (int i = 0; i < 7; ++i) cf[i] = w7[(c - 192) * 7 + i];
    }
    int cnt = 0;
    #pragma unroll
    for (int i = 0; i < 7; ++i) cnt += (cf[i] != 0.f);

    __shared__ int sc[256];
    sc[c] = cnt;
    __syncthreads();
    for (int off = 1; off < 256; off <<= 1) {
        int u = 0;
        if (c >= off) u = sc[c - off];
        __syncthreads();
        sc[c] += u;
        __syncthreads();
    }
    const int start = sc[c] - cnt;
    int J = sc[255];
    if (J > KMAX) J = KMAX;
    int Kpad = (J + 31) & ~31;
    if (Kpad > KMAX) Kpad = KMAX;
    if (c == 0) { meta[0] = (unsigned int)Kpad; meta[1] = (unsigned int)J; }

    int j = start;
    #pragma unroll
    for (int i = 0; i < 7; ++i) {
        if (cf[i] != 0.f) {
            if (j < KMAX) {
                idx[j] = (unsigned int)c | ((unsigned int)i << 8);
                cval[j] = cf[i];
                const int dt  = i - 3;
                const int lin = (dt * C_TOT + c) * (HW_ * 4);
                #pragma unroll
                for (int tt = 0; tt < 8; ++tt) {
                    const int tf = tt + dt;
                    offt[tt * KMAX + j] =
                        (tf >= 0 && tf < 8) ? (unsigned int)lin : MARKER;
                }
            }
            ++j;
        }
    }
    for (int p = J + c; p < Kpad; p += 256) {
        idx[p] = 3u << 8;
        cval[p] = 0.f;
        #pragma unroll
        for (int tt = 0; tt < 8; ++tt) offt[tt * KMAX + p] = MARKER;
    }
}

// ---- pre-pass 2: A3 fragment-major: A3[(slot*256+o)*8+e], slot=kk*4+koct ----
__global__ __launch_bounds__(256)
void build_A3(const float* __restrict__ netw, const unsigned int* __restrict__ meta,
              const unsigned int* __restrict__ idx, const float* __restrict__ cval,
              unsigned short* __restrict__ A3)
{
    const int o = blockIdx.x;
    const int Kpad   = (int)meta[0];
    const int nslots = Kpad >> 3;
    for (int s = threadIdx.x; s < nslots; s += 256) {
        unsigned short v[8];
        #pragma unroll
        for (int e = 0; e < 8; ++e) {
            const int jj = s * 8 + e;
            const int c  = (int)(idx[jj] & 255u);
            v[e] = f2b(netw[o * C_TOT + c] * cval[jj]);
        }
        *reinterpret_cast<u32x4*>(&A3[((size_t)s * 256 + o) * 8]) =
            *reinterpret_cast<const u32x4*>(v);
    }
}

// ---- barrier-free gather GEMM, register-lean (target: arch VGPR <= 64) ----
// Block = one frame x one 64-px tile; wave = one 64-o group, fully independent.
// Compute streamed per ns-slice (gather 8 -> pack -> 4 MFMA); acc = 64 AGPR;
// total <=128 regs -> one occupancy step up (2 -> 4 waves/SIMD).
__global__ __launch_bounds__(256, 4)
void msce_gather(const float* __restrict__ x,
                 const unsigned short* __restrict__ A3,
                 const unsigned int* __restrict__ offt,
                 const unsigned int* __restrict__ meta,
                 const float* __restrict__ net_b,
                 float* __restrict__ out)
{
    const int Kpad = (int)meta[0];
    const int KK   = Kpad >> 5;

    const int tid  = threadIdx.x;
    const int wave = tid >> 6;       // = o-group 0..3
    const int lane = tid & 63;

#if USE_RAW_BUF
    const __amdgpu_buffer_rsrc_t rsrc =
        __builtin_amdgcn_make_buffer_rsrc((void*)x, (short)0,
                                          (int)XBYTES, 0x00020000);
    #define GLOAD(ofs) __builtin_bit_cast(float, \
        __builtin_amdgcn_raw_buffer_load_b32(rsrc, (int)(ofs), 0, 0))
#else
    #define GLOAD(ofs) (((ofs) < (unsigned int)XBYTES) ? x[(ofs) >> 2] : 0.f)
#endif

    // bijective XCD swizzle: 1664 = 8 x 208 -> 16 consecutive frames per XCD
    const int bid  = blockIdx.x;
    const int work = (bid & 7) * 208 + (bid >> 3);
    const int n    = work / 13;
    const int tile = work - n * 13;
    const int p0   = (tile < 12) ? tile * 64 : 720;   // tile 12 overlaps 11 (benign)
    const int t    = n & 7;

    const int og   = wave;
    const int koct = lane >> 4;
    const int prow = lane & 15;
    // single per-lane pixel base; ns adds a literal ns*64 bytes
    const unsigned int pbase =
        (unsigned int)n * (unsigned int)(C_TOT * HW_ * 4)
        + (unsigned int)((p0 + prow) * 4);
    const unsigned int* offrow = offt + (size_t)t * KMAX;

    // acc init = bias (D layout: col=prow, row = og*64 + ms*16 + koct*4 + r)
    f32x4 acc[4][4];
    #pragma unroll
    for (int ms = 0; ms < 4; ++ms) {
        const f32x4 b = *reinterpret_cast<const f32x4*>(
                            &net_b[og * 64 + ms * 16 + koct * 4]);
        #pragma unroll
        for (int ns = 0; ns < 4; ++ns) acc[ms][ns] = b;
    }

    auto step = [&](int kk) {
        // 8 relative row offsets for this lane's k-octet (L1-hot table)
        unsigned int o8[8];
        #pragma unroll
        for (int e = 0; e < 8; ++e)
            o8[e] = offrow[kk * 32 + koct * 8 + e];

        // A-fragments: fragment-major, 16 lanes read 256B contiguous
        short8 af[4];
        const unsigned short* abase =
            A3 + ((size_t)(kk * 4 + koct) * 256 + og * 64 + prow) * 8;
        #pragma unroll
        for (int ms = 0; ms < 4; ++ms)
            af[ms] = *reinterpret_cast<const short8*>(abase + (size_t)ms * 128);

        // streamed ns-slices: gather 8 -> pack -> 4 MFMA (small live set)
        #pragma unroll
        for (int ns = 0; ns < 4; ++ns) {
            float g[8];
            #pragma unroll
            for (int e = 0; e < 8; ++e)
                g[e] = GLOAD(o8[e] + pbase + (unsigned int)(ns * 64));
            u32x4 bw;
            bw[0] = pk2(g[0], g[1]);
            bw[1] = pk2(g[2], g[3]);
            bw[2] = pk2(g[4], g[5]);
            bw[3] = pk2(g[6], g[7]);
            const short8 bfr = __builtin_bit_cast(short8, bw);
            #pragma unroll
            for (int ms = 0; ms < 4; ++ms)
                acc[ms][ns] = __builtin_amdgcn_mfma_f32_16x16x32_bf16(
                                  af[ms], bfr, acc[ms][ns], 0, 0, 0);
        }
    };

    if (Kpad == KPAD_STD) {
        #pragma unroll
        for (int kk = 0; kk < 10; ++kk) step(kk);
    } else {
        for (int kk = 0; kk < KK; ++kk) step(kk);
    }
    #undef GLOAD

    // ---- store: out[n][o][p], f32 ----
    #pragma unroll
    for (int ns = 0; ns < 4; ++ns) {
        const int p = p0 + ns * 16 + prow;
        #pragma unroll
        for (int ms = 0; ms < 4; ++ms) {
            const int o = og * 64 + ms * 16 + koct * 4;
            const size_t base = ((size_t)n * O_TOT + o) * HW_ + p;
            #pragma unroll
            for (int r = 0; r < 4; ++r)
                out[base + (size_t)r * HW_] = acc[ms][ns][r];
        }
    }
}

extern "C" void kernel_launch(void* const* d_in, const int* in_sizes, int n_in,
                              void* d_out, int out_size, void* d_ws, size_t ws_size,
                              hipStream_t stream) {
    const float* x    = (const float*)d_in[0];
    const float* w3p  = (const float*)d_in[1];
    const float* w5p  = (const float*)d_in[2];
    const float* w7p  = (const float*)d_in[3];
    const float* netw = (const float*)d_in[4];
    const float* netb = (const float*)d_in[5];
    float* outp = (float*)d_out;

    char* ws = (char*)d_ws;
    unsigned int*   meta = (unsigned int*)ws;
    unsigned int*   idx  = (unsigned int*)(ws + WS_IDX_OFF);
    float*          cval = (float*)(ws + WS_CVAL_OFF);
    unsigned int*   offt = (unsigned int*)(ws + WS_OFFT_OFF);
    unsigned short* A3   = (unsigned short*)(ws + WS_A3_OFF);

    hipLaunchKernelGGL(build_idx, dim3(1), dim3(256), 0, stream,
                       w3p, w5p, w7p, meta, idx, cval, offt);
    hipLaunchKernelGGL(build_A3, dim3(256), dim3(256), 0, stream,
                       netw, meta, idx, cval, A3);

    hipLaunchKernelGGL(msce_gather, dim3(1664), dim3(256), 0, stream,
                       x, A3, offt, meta, netb, outp);
}

// Round 17
// 52.203 us; speedup vs baseline: 1.3868x; 1.3868x over previous
//
#include <hip/hip_runtime.h>
#include <hip/hip_bf16.h>

typedef __attribute__((ext_vector_type(8))) short short8;
typedef __attribute__((ext_vector_type(4))) float f32x4;
typedef __attribute__((ext_vector_type(4))) unsigned int u32x4;

#define C_TOT 256
#define O_TOT 256
#define HW_   784
#define NT_   128
#define KMAX  1792
#define KPAD_STD 320          // 304 real taps (128+80+96) padded to 32 -> 10 K-steps
#define XBYTES (NT_ * C_TOT * HW_ * 4)
#define MARKER 0x60000000u

// ws layout (bytes):
//   meta  u32[4]               @ 0
//   idx   u32[KMAX]            @ WS_IDX_OFF
//   cval  f32[KMAX]            @ WS_CVAL_OFF
//   offt  u32[8][KMAX]         @ WS_OFFT_OFF  per-t relative byte offsets (or MARKER)
//   A3    bf16[KMAX*256]       @ WS_A3_OFF    fragment-major
//   zpage f32[256]             @ WS_ZERO_OFF  zero rows for MARKER taps
#define WS_IDX_OFF  16
#define WS_CVAL_OFF (WS_IDX_OFF + 4 * KMAX)
#define WS_OFFT_OFF (WS_CVAL_OFF + 4 * KMAX)
#define WS_A3_OFF   (WS_OFFT_OFF + 4 * 8 * KMAX)
#define WS_ZERO_OFF (WS_A3_OFF + 512 * KMAX)

#if __has_builtin(__builtin_amdgcn_global_load_lds)
#define USE_DMA 1
#else
#define USE_DMA 0
#endif

__device__ __forceinline__ unsigned int pk2(float lo, float hi) {
    float2 f; f.x = lo; f.y = hi;
    __hip_bfloat162 h = __float22bfloat162_rn(f);   // v_cvt_pk_bf16_f32
    unsigned int r;
    __builtin_memcpy(&r, &h, 4);
    return r;
}
__device__ __forceinline__ unsigned short f2b(float f) {
    union { float f; unsigned int u; } cv; cv.f = f;
    unsigned int u = cv.u;
    u += 0x7fffu + ((u >> 16) & 1u);
    return (unsigned short)(u >> 16);
}

// ---- pre-pass 1: tap enumeration + per-t offset tables + zero page ----
__global__ __launch_bounds__(256)
void build_idx(const float* __restrict__ w3, const float* __restrict__ w5,
               const float* __restrict__ w7, unsigned int* __restrict__ meta,
               unsigned int* __restrict__ idx, float* __restrict__ cval,
               unsigned int* __restrict__ offt, float* __restrict__ zpage)
{
    const int c = threadIdx.x;
    zpage[c] = 0.f;   // 256 floats = 1KB zero page

    float cf[7];
    #pragma unroll
    for (int i = 0; i < 7; ++i) cf[i] = 0.f;
    if (c < 128) {
        #pragma unroll
        for (int i = 0; i < 3; ++i) cf[i + 2] = w3[c * 3 + i];
    } else if (c < 192) {
        #pragma unroll
        for (int i = 0; i < 5; ++i) cf[i + 1] = w5[(c - 128) * 5 + i];
    } else {
        #pragma unroll
        for (int i = 0; i < 7; ++i) cf[i] = w7[(c - 192) * 7 + i];
    }
    int cnt = 0;
    #pragma unroll
    for (int i = 0; i < 7; ++i) cnt += (cf[i] != 0.f);

    __shared__ int sc[256];
    sc[c] = cnt;
    __syncthreads();
    for (int off = 1; off < 256; off <<= 1) {
        int u = 0;
        if (c >= off) u = sc[c - off];
        __syncthreads();
        sc[c] += u;
        __syncthreads();
    }
    const int start = sc[c] - cnt;
    int J = sc[255];
    if (J > KMAX) J = KMAX;
    int Kpad = (J + 31) & ~31;
    if (Kpad > KMAX) Kpad = KMAX;
    if (c == 0) { meta[0] = (unsigned int)Kpad; meta[1] = (unsigned int)J; }

    int j = start;
    #pragma unroll
    for (int i = 0; i < 7; ++i) {
        if (cf[i] != 0.f) {
            if (j < KMAX) {
                idx[j] = (unsigned int)c | ((unsigned int)i << 8);
                cval[j] = cf[i];
                const int dt  = i - 3;
                const int lin = (dt * C_TOT + c) * (HW_ * 4);
                #pragma unroll
                for (int tt = 0; tt < 8; ++tt) {
                    const int tf = tt + dt;
                    offt[tt * KMAX + j] =
                        (tf >= 0 && tf < 8) ? (unsigned int)lin : MARKER;
                }
            }
            ++j;
        }
    }
    for (int p = J + c; p < Kpad; p += 256) {
        idx[p] = 3u << 8;
        cval[p] = 0.f;
        #pragma unroll
        for (int tt = 0; tt < 8; ++tt) offt[tt * KMAX + p] = MARKER;
    }
}

// ---- pre-pass 2: A3 fragment-major: A3[(slot*256+o)*8+e], slot=kk*4+koct ----
__global__ __launch_bounds__(256)
void build_A3(const float* __restrict__ netw, const unsigned int* __restrict__ meta,
              const unsigned int* __restrict__ idx, const float* __restrict__ cval,
              unsigned short* __restrict__ A3)
{
    const int o = blockIdx.x;
    const int Kpad   = (int)meta[0];
    const int nslots = Kpad >> 3;
    for (int s = threadIdx.x; s < nslots; s += 256) {
        unsigned short v[8];
        #pragma unroll
        for (int e = 0; e < 8; ++e) {
            const int jj = s * 8 + e;
            const int c  = (int)(idx[jj] & 255u);
            v[e] = f2b(netw[o * C_TOT + c] * cval[jj]);
        }
        *reinterpret_cast<u32x4*>(&A3[((size_t)s * 256 + o) * 8]) =
            *reinterpret_cast<const u32x4*>(v);
    }
}

// ---- fused GEMM with global_load_lds DMA staging (Kpad=320 path) ----
// Block = frame x 64-px tile; 4 waves, each 64(o) x 64(p), K=320 in 10 steps.
// Per step: wave stages its 8 B-rows via 2 global_load_lds_dwordx4 (depth-2,
// 3 LDS bufs), counted vmcnt (never 0 mid-loop), raw barriers, padded LDS.
__global__ __launch_bounds__(256, 2)
void msce_dma(const float* __restrict__ x,
              const unsigned short* __restrict__ A3,
              const unsigned int* __restrict__ offt,
              const unsigned int* __restrict__ meta,
              const float* __restrict__ net_b,
              const float* __restrict__ zpage,
              float* __restrict__ out)
{
    // 3 bufs x 8 groups x (4 rows x 256B + 16B pad) = 3 x 2080 dwords
    __shared__ unsigned int Bl[3][2080];

    const int Kpad = (int)meta[0];
    const int tid  = threadIdx.x;
    const int w    = tid >> 6;
    const int lane = tid & 63;

    // bijective XCD swizzle: 1664 = 8 x 208
    const int bid  = blockIdx.x;
    const int work = (bid & 7) * 208 + (bid >> 3);
    const int n    = work / 13;
    const int tile = work - n * 13;
    const int p0   = (tile < 12) ? tile * 64 : 720;
    const int t    = n & 7;

    const int koct = lane >> 4;   // also row-in-quad for staging
    const int prow = lane & 15;
    const unsigned int pc16  = (unsigned int)(prow * 16);
    const unsigned int n_off = (unsigned int)n * (unsigned int)(C_TOT * HW_ * 4);
    const unsigned int p04   = (unsigned int)(p0 * 4);
    const unsigned int* offrow = offt + (size_t)t * KMAX;

    // acc init = bias (D: col=prow=pixel, row = w*64 + ms*16 + koct*4 + r)
    f32x4 acc[4][4];
    #pragma unroll
    for (int ms = 0; ms < 4; ++ms) {
        const f32x4 b = *reinterpret_cast<const f32x4*>(
                            &net_b[w * 64 + ms * 16 + koct * 4]);
        #pragma unroll
        for (int ns = 0; ns < 4; ++ns) acc[ms][ns] = b;
    }

    auto ldaf = [&](int kk, short8* af) {
        const unsigned short* abase =
            A3 + ((size_t)(kk * 4 + koct) * 256 + w * 64 + prow) * 8;
        #pragma unroll
        for (int ms = 0; ms < 4; ++ms)
            af[ms] = *reinterpret_cast<const short8*>(abase + (size_t)ms * 128);
    };

    auto comp = [&](int bsel, const short8* af) {
        const int rowbase = koct * 520;          // koct*2 groups * 260 dw
        #pragma unroll
        for (int ns = 0; ns < 4; ++ns) {
            const int cb = ns * 16 + prow;
            float gg[8];
            #pragma unroll
            for (int e = 0; e < 8; ++e)
                gg[e] = __builtin_bit_cast(float,
                    Bl[bsel][rowbase + (e >> 2) * 260 + (e & 3) * 64 + cb]);
            u32x4 bw;
            bw[0] = pk2(gg[0], gg[1]);
            bw[1] = pk2(gg[2], gg[3]);
            bw[2] = pk2(gg[4], gg[5]);
            bw[3] = pk2(gg[6], gg[7]);
            const short8 bfr = __builtin_bit_cast(short8, bw);
            #pragma unroll
            for (int ms = 0; ms < 4; ++ms)
                acc[ms][ns] = __builtin_amdgcn_mfma_f32_16x16x32_bf16(
                                  af[ms], bfr, acc[ms][ns], 0, 0, 0);
        }
    };

#if USE_DMA
    if (Kpad == KPAD_STD) {
        // per-lane stage offsets for all 10 steps x 2 quads (row = w*8+q*4+koct)
        unsigned int offa[20];
        #pragma unroll
        for (int i = 0; i < 20; ++i)
            offa[i] = offrow[(i >> 1) * 32 + w * 8 + (i & 1) * 4 + koct];

        const char* xb = (const char*)x;
        const char* zb = (const char*)zpage;

        auto stage1 = [&](unsigned int off, int buf, int q) {
            const char* src = (off != MARKER)
                            ? xb + (n_off + off + p04 + pc16)
                            : zb + pc16;
            unsigned int* dst = &Bl[buf][(w * 2 + q) * 260];
            __builtin_amdgcn_global_load_lds(
                (const __attribute__((address_space(1))) unsigned int*)src,
                (__attribute__((address_space(3))) unsigned int*)dst, 16, 0, 0);
        };

        short8 af0[4], af1[4];

        // prologue: stage(0)->buf0, stage(1)->buf1, afrag(0)
        stage1(offa[0], 0, 0); stage1(offa[1], 0, 1);
        stage1(offa[2], 1, 0); stage1(offa[3], 1, 1);
        ldaf(0, af0);

#define BAR1() do { \
    asm volatile("s_waitcnt lgkmcnt(0)" ::: "memory"); \
    __builtin_amdgcn_s_barrier(); \
    __builtin_amdgcn_sched_barrier(0); } while (0)
#define BAR2(VN) do { \
    asm volatile("s_waitcnt vmcnt(" #VN ")" ::: "memory"); \
    __builtin_amdgcn_s_barrier(); \
    __builtin_amdgcn_sched_barrier(0); } while (0)
#define STEP(KK, VN, AFC, AFN) do { \
    BAR1(); \
    if ((KK) + 2 < 10) { \
        stage1(offa[2 * ((KK) + 2)],     ((KK) + 2) % 3, 0); \
        stage1(offa[2 * ((KK) + 2) + 1], ((KK) + 2) % 3, 1); \
    } \
    if ((KK) + 1 < 10) ldaf((KK) + 1, AFN); \
    BAR2(VN); \
    comp((KK) % 3, AFC); } while (0)

        STEP(0, 12, af0, af1);
        STEP(1, 12, af1, af0);
        STEP(2, 12, af0, af1);
        STEP(3, 12, af1, af0);
        STEP(4, 12, af0, af1);
        STEP(5, 12, af1, af0);
        STEP(6, 12, af0, af1);
        STEP(7, 12, af1, af0);
        STEP(8, 10, af0, af1);
        STEP(9, 4, af1, af0);
#undef STEP
#undef BAR2
#undef BAR1
    } else
#endif
    {
        // generic fallback: direct bounds-checked gathers (round-12 structure)
        const int KK = Kpad >> 5;
        for (int kk = 0; kk < KK; ++kk) {
            unsigned int o8[8];
            #pragma unroll
            for (int e = 0; e < 8; ++e)
                o8[e] = offrow[kk * 32 + koct * 8 + e];
            short8 af[4];
            ldaf(kk, af);
            #pragma unroll
            for (int ns = 0; ns < 4; ++ns) {
                const unsigned int pofs = n_off + (unsigned int)((p0 + ns * 16 + prow) * 4);
                float g[8];
                #pragma unroll
                for (int e = 0; e < 8; ++e) {
                    const unsigned int of = o8[e] + pofs;
                    g[e] = (o8[e] != MARKER && of < (unsigned int)XBYTES)
                         ? x[of >> 2] : 0.f;
                }
                u32x4 bw;
                bw[0] = pk2(g[0], g[1]);
                bw[1] = pk2(g[2], g[3]);
                bw[2] = pk2(g[4], g[5]);
                bw[3] = pk2(g[6], g[7]);
                const short8 bfr = __builtin_bit_cast(short8, bw);
                #pragma unroll
                for (int ms = 0; ms < 4; ++ms)
                    acc[ms][ns] = __builtin_amdgcn_mfma_f32_16x16x32_bf16(
                                      af[ms], bfr, acc[ms][ns], 0, 0, 0);
            }
        }
    }

    // ---- store: out[n][o][p], f32 ----
    #pragma unroll
    for (int ns = 0; ns < 4; ++ns) {
        const int p = p0 + ns * 16 + prow;
        #pragma unroll
        for (int ms = 0; ms < 4; ++ms) {
            const int o = w * 64 + ms * 16 + koct * 4;
            const size_t base = ((size_t)n * O_TOT + o) * HW_ + p;
            #pragma unroll
            for (int r = 0; r < 4; ++r)
                out[base + (size_t)r * HW_] = acc[ms][ns][r];
        }
    }
}

extern "C" void kernel_launch(void* const* d_in, const int* in_sizes, int n_in,
                              void* d_out, int out_size, void* d_ws, size_t ws_size,
                              hipStream_t stream) {
    const float* x    = (const float*)d_in[0];
    const float* w3p  = (const float*)d_in[1];
    const float* w5p  = (const float*)d_in[2];
    const float* w7p  = (const float*)d_in[3];
    const float* netw = (const float*)d_in[4];
    const float* netb = (const float*)d_in[5];
    float* outp = (float*)d_out;

    char* ws = (char*)d_ws;
    unsigned int*   meta  = (unsigned int*)ws;
    unsigned int*   idx   = (unsigned int*)(ws + WS_IDX_OFF);
    float*          cval  = (float*)(ws + WS_CVAL_OFF);
    unsigned int*   offt  = (unsigned int*)(ws + WS_OFFT_OFF);
    unsigned short* A3    = (unsigned short*)(ws + WS_A3_OFF);
    float*          zpage = (float*)(ws + WS_ZERO_OFF);

    hipLaunchKernelGGL(build_idx, dim3(1), dim3(256), 0, stream,
                       w3p, w5p, w7p, meta, idx, cval, offt, zpage);
    hipLaunchKernelGGL(build_A3, dim3(256), dim3(256), 0, stream,
                       netw, meta, idx, cval, A3);

    hipLaunchKernelGGL(msce_dma, dim3(1664), dim3(256), 0, stream,
                       x, A3, offt, meta, netb, zpage, outp);
}